// Round 12
// baseline (1317.025 us; speedup 1.0000x reference)
//
#include <hip/hip_runtime.h>

#define SEQ 2048
#define BATCH 512
#define HDIM 128

typedef __bf16 bf16x8 __attribute__((ext_vector_type(8)));
typedef float  f32x4  __attribute__((ext_vector_type(4)));
typedef unsigned int uint32;

// tanh with input pre-scaled by 2*log2(e): tanh(x) = 1 - 2/(2^(CS*x)+1).
__device__ __forceinline__ float tanh_e2(float y) {
    float e;
    asm("v_exp_f32 %0, %1" : "=v"(e) : "v"(y));
    return fmaf(-2.0f, __builtin_amdgcn_rcpf(e + 1.0f), 1.0f);
}

// x + dpp(x); bound_ctrl=true.
template<int CTRL>
__device__ __forceinline__ float dpp_add(float x) {
    return x + __int_as_float(__builtin_amdgcn_update_dpp(
        0, __float_as_int(x), CTRL, 0xf, 0xf, true));
}

__global__ __launch_bounds__(256, 1)
void odenet_scan_kernel(const float* __restrict__ x,
                        const float* __restrict__ W1,
                        const float* __restrict__ b1,
                        const float* __restrict__ W2,
                        const float* __restrict__ b2,
                        const float* __restrict__ W3,
                        const float* __restrict__ b3,
                        float* __restrict__ out)
{
    const int t  = threadIdx.x;
    const int l  = t & 63;           // lane
    const int wv = t >> 6;           // wave 0..3: owns output cols [32wv, 32wv+32)
    const int b0 = 2 * blockIdx.x;   // two chains per block: b0, b0+1

    constexpr float CS = 2.8853900817779268f;   // 2*log2(e) tanh prefold

    __shared__ float2 xbuf[SEQ];                          // 16 KB
    __shared__ unsigned short hbuf[4][2][3 * HDIM];       // [wave][hi|lo][row*128+k]; row2 = zeros
    __shared__ __align__(16) float2 ybuf[2][4];           // [parity][wave] = {yA, yB}

    // ---- one-time: preload x for both chains.
    #pragma unroll
    for (int i = 0; i < 8; ++i)
        xbuf[i * 256 + t] = *reinterpret_cast<const float2*>(&x[(i * 256 + t) * BATCH + b0]);

    // ---- one-time: zero the dummy A-row (row 2) of this wave's h buffers.
    reinterpret_cast<uint32*>(&hbuf[wv][0][2 * HDIM])[l] = 0u;   // 128 ushorts = 64 uints
    reinterpret_cast<uint32*>(&hbuf[wv][1][2 * HDIM])[l] = 0u;

    // ---- one-time: B fragments (CS*W2 split into bf16 hi/lo), pinned in regs.
    // B[k][n] layout for 16x16x32: lane holds col=l&15, k = 32*kt + 8*(l>>4) + j.
    bf16x8 Bhi[2][4], Blo[2][4];
    #pragma unroll
    for (int nt = 0; nt < 2; ++nt) {
        #pragma unroll
        for (int kt = 0; kt < 4; ++kt) {
            union { unsigned short u[8]; bf16x8 v; } fh, fl;
            #pragma unroll
            for (int j = 0; j < 8; ++j) {
                const int k = 32 * kt + 8 * (l >> 4) + j;
                const int c = 32 * wv + 16 * nt + (l & 15);
                const float v = W2[k * HDIM + c] * CS;
                const uint32 u = __float_as_uint(v);
                fh.u[j] = (unsigned short)(u >> 16);                       // truncate hi
                const float hif = __uint_as_float(u & 0xffff0000u);
                fl.u[j] = (unsigned short)(__float_as_uint(v - hif) >> 16); // truncate lo
            }
            Bhi[nt][kt] = fh.v;
            Blo[nt][kt] = fl.v;
        }
    }

    // ---- h1 params: this lane computes chain (l>>5), cols cc..cc+3 (prescaled CS).
    const int cc = 4 * (l & 31);
    float4 w1xv = *reinterpret_cast<const float4*>(&W1[cc]);
    float4 w1sv = *reinterpret_cast<const float4*>(&W1[HDIM + cc]);
    float4 b1v  = *reinterpret_cast<const float4*>(&b1[cc]);
    w1xv.x *= CS; w1xv.y *= CS; w1xv.z *= CS; w1xv.w *= CS;
    w1sv.x *= CS; w1sv.y *= CS; w1sv.z *= CS; w1sv.w *= CS;
    b1v.x  *= CS; b1v.y  *= CS; b1v.z  *= CS; b1v.w  *= CS;

    // ---- layer-2/3 params for this lane's two C-columns (cz, cz+16).
    const int cz = 32 * wv + (l & 15);
    const float b2a = b2[cz] * CS,  b2b = b2[cz + 16] * CS;
    const float w3a = W3[2 * cz + 1], w3b = W3[2 * (cz + 16) + 1];
    const float b31 = b3[1];

    // ---- LDS addresses.
    // write: h for (chain, cols cc..cc+3) -> hbuf[wv][*][chain*128 + cc]
    const int chain = l >> 5;
    unsigned short* pWh = &hbuf[wv][0][chain * HDIM + cc];
    unsigned short* pWl = &hbuf[wv][1][chain * HDIM + cc];
    // read: A-frag row = l&15 (rows >=2 -> zero row 2), k-window 8*(l>>4).
    const int rowe = ((l & 15) < 2) ? (l & 15) : 2;
    const unsigned short* pAh = &hbuf[wv][0][rowe * HDIM + 8 * (l >> 4)];
    const unsigned short* pAl = &hbuf[wv][1][rowe * HDIM + 8 * (l >> 4)];

    __syncthreads();

    float sA = 0.0f, sB = 0.0f, s_hold = 0.0f;

    for (int n = 0; n < SEQ; ++n) {
        const int par = n & 1;

        // ---- layer 1: 4 cols of this lane's chain (redundant per wave).
        const float2 xn = xbuf[n];
        const float xC = (l & 32) ? xn.y : xn.x;
        const float sC = (l & 32) ? sB : sA;
        const float h0 = tanh_e2(fmaf(w1sv.x, sC, fmaf(w1xv.x, xC, b1v.x)));
        const float h1 = tanh_e2(fmaf(w1sv.y, sC, fmaf(w1xv.y, xC, b1v.y)));
        const float h2 = tanh_e2(fmaf(w1sv.z, sC, fmaf(w1xv.z, xC, b1v.z)));
        const float h3 = tanh_e2(fmaf(w1sv.w, sC, fmaf(w1xv.w, xC, b1v.w)));

        // ---- split to bf16 hi/lo (truncation; lo captures the remainder).
        const uint32 u0 = __float_as_uint(h0), u1 = __float_as_uint(h1);
        const uint32 u2 = __float_as_uint(h2), u3 = __float_as_uint(h3);
        const uint32 hi01 = __builtin_amdgcn_perm(u1, u0, 0x07060302u);
        const uint32 hi23 = __builtin_amdgcn_perm(u3, u2, 0x07060302u);
        const float r0 = h0 - __uint_as_float(u0 & 0xffff0000u);
        const float r1 = h1 - __uint_as_float(u1 & 0xffff0000u);
        const float r2 = h2 - __uint_as_float(u2 & 0xffff0000u);
        const float r3 = h3 - __uint_as_float(u3 & 0xffff0000u);
        const uint32 lo01 = __builtin_amdgcn_perm(__float_as_uint(r1), __float_as_uint(r0), 0x07060302u);
        const uint32 lo23 = __builtin_amdgcn_perm(__float_as_uint(r3), __float_as_uint(r2), 0x07060302u);
        *reinterpret_cast<uint2*>(pWh) = make_uint2(hi01, hi23);
        *reinterpret_cast<uint2*>(pWl) = make_uint2(lo01, lo23);
        __builtin_amdgcn_wave_barrier();   // in-wave LDS write -> read order

        // ---- matvec on the matrix pipe: p = CS*(W2^T h) + CS*b2 (C-init).
        f32x4 C0 = {b2a, b2a, b2a, b2a};
        f32x4 C1 = {b2b, b2b, b2b, b2b};
        #pragma unroll
        for (int kt = 0; kt < 4; ++kt) {
            const bf16x8 ah = __builtin_bit_cast(bf16x8,
                *reinterpret_cast<const uint4*>(pAh + 32 * kt));
            const bf16x8 al = __builtin_bit_cast(bf16x8,
                *reinterpret_cast<const uint4*>(pAl + 32 * kt));
            C0 = __builtin_amdgcn_mfma_f32_16x16x32_bf16(ah, Bhi[0][kt], C0, 0, 0, 0);
            C1 = __builtin_amdgcn_mfma_f32_16x16x32_bf16(ah, Bhi[1][kt], C1, 0, 0, 0);
            C0 = __builtin_amdgcn_mfma_f32_16x16x32_bf16(al, Bhi[0][kt], C0, 0, 0, 0);
            C1 = __builtin_amdgcn_mfma_f32_16x16x32_bf16(al, Bhi[1][kt], C1, 0, 0, 0);
            C0 = __builtin_amdgcn_mfma_f32_16x16x32_bf16(ah, Blo[0][kt], C0, 0, 0, 0);
            C1 = __builtin_amdgcn_mfma_f32_16x16x32_bf16(ah, Blo[1][kt], C1, 0, 0, 0);
        }

        // ---- h2 tanh + W3 col-1 dot. Real chains = rows 0,1 = regs 0,1 of
        //      lane-group 0; other lanes compute garbage harmlessly.
        float zc0 = fmaf(tanh_e2(C1[0]), w3b, tanh_e2(C0[0]) * w3a);  // chain A
        float zc1 = fmaf(tanh_e2(C1[1]), w3b, tanh_e2(C0[1]) * w3a);  // chain B

        // ---- reduce over the 16 cols (lane&15) of this wave's two N-tiles.
        zc0 = dpp_add<0xB1>(zc0);  zc1 = dpp_add<0xB1>(zc1);   // xor1
        zc0 = dpp_add<0x4E>(zc0);  zc1 = dpp_add<0x4E>(zc1);   // xor2
        zc0 = dpp_add<0x141>(zc0); zc1 = dpp_add<0x141>(zc1);  // half-mirror (cross-quad)
        zc0 = dpp_add<0x140>(zc0); zc1 = dpp_add<0x140>(zc1);  // mirror (cross-8)

        if (l == 0) ybuf[par][wv] = make_float2(zc0, zc1);
        __syncthreads();   // the ONLY block barrier per step

        const float4 y01 = *reinterpret_cast<const float4*>(&ybuf[par][0]);
        const float4 y23 = *reinterpret_cast<const float4*>(&ybuf[par][2]);
        sA += ((y01.x + y01.z) + (y23.x + y23.z)) + b31;
        sB += ((y01.y + y01.w) + (y23.y + y23.w)) + b31;

        // ---- out batching: wave0 stores chain A, wave1 chain B.
        if (wv < 2) {
            if (l == (n & 63)) s_hold = wv ? sB : sA;
            if ((n & 63) == 63) out[(n - 63 + l) * BATCH + b0 + wv] = s_hold;
        }
    }
}

extern "C" void kernel_launch(void* const* d_in, const int* in_sizes, int n_in,
                              void* d_out, int out_size, void* d_ws, size_t ws_size,
                              hipStream_t stream) {
    const float* x  = (const float*)d_in[0];
    const float* W1 = (const float*)d_in[1];
    const float* b1 = (const float*)d_in[2];
    const float* W2 = (const float*)d_in[3];
    const float* b2 = (const float*)d_in[4];
    const float* W3 = (const float*)d_in[5];
    const float* b3 = (const float*)d_in[6];
    float* out = (float*)d_out;

    dim3 grid(BATCH / 2);   // two chains per block
    dim3 block(256);        // 4 waves, N=32 cols each
    odenet_scan_kernel<<<grid, block, 0, stream>>>(x, W1, b1, W2, b2, W3, b3, out);
}

// Round 13
// 936.369 us; speedup vs baseline: 1.4065x; 1.4065x over previous
//
#include <hip/hip_runtime.h>

#define SEQ 2048
#define BATCH 512
#define HDIM 128

typedef __bf16 bf16x8 __attribute__((ext_vector_type(8)));
typedef float  f32x4  __attribute__((ext_vector_type(4)));
typedef unsigned int uint32;

// tanh with input pre-scaled by 2*log2(e): tanh(x) = 1 - 2/(2^(CS*x)+1).
__device__ __forceinline__ float tanh_e2(float y) {
    float e;
    asm("v_exp_f32 %0, %1" : "=v"(e) : "v"(y));
    return fmaf(-2.0f, __builtin_amdgcn_rcpf(e + 1.0f), 1.0f);
}

// x + dpp(x); bound_ctrl=true.
template<int CTRL>
__device__ __forceinline__ float dpp_add(float x) {
    return x + __int_as_float(__builtin_amdgcn_update_dpp(
        0, __float_as_int(x), CTRL, 0xf, 0xf, true));
}

__global__ __launch_bounds__(256, 2)
void odenet_scan_kernel(const float* __restrict__ x,
                        const float* __restrict__ W1,
                        const float* __restrict__ b1,
                        const float* __restrict__ W2,
                        const float* __restrict__ b2,
                        const float* __restrict__ W3,
                        const float* __restrict__ b3,
                        float* __restrict__ out)
{
    const int t  = threadIdx.x;
    const int l  = t & 63;           // lane
    const int wv = t >> 6;           // wave 0..3: owns output cols [32wv, 32wv+32)
    const int b  = blockIdx.x;       // ONE chain per block; grid=512 -> 2 blocks/CU

    constexpr float CS = 2.8853900817779268f;   // 2*log2(e) tanh prefold

    __shared__ float xbuf[SEQ];                        // 8 KB: all x for this chain
    // A-matrix staging: row0 = h_hi (bf16), row1 = h_lo. Row stride 144 ushorts
    // = 288 B = 72 banks === 8 (mod 32): row0/row1 readers hit disjoint banks.
    __shared__ unsigned short hbuf[4][2][144];         // [wave][row][k padded]
    __shared__ __align__(16) float ybuf[2][4];         // [parity][wave] y-partials

    // ---- one-time: preload x.
    #pragma unroll
    for (int i = 0; i < 8; ++i)
        xbuf[i * 256 + t] = x[(i * 256 + t) * BATCH + b];

    // ---- one-time: B fragments (CS*W2 split into bf16 hi/lo), pinned in regs.
    // 16x16x32 B-frag: lane holds col = l&15, k = 32*kt + 8*(l>>4) + j.
    bf16x8 Bhi[2][4], Blo[2][4];
    #pragma unroll
    for (int nt = 0; nt < 2; ++nt) {
        #pragma unroll
        for (int kt = 0; kt < 4; ++kt) {
            union { unsigned short u[8]; bf16x8 v; } fh, fl;
            #pragma unroll
            for (int j = 0; j < 8; ++j) {
                const int k = 32 * kt + 8 * (l >> 4) + j;
                const int c = 32 * wv + 16 * nt + (l & 15);
                const float v = W2[k * HDIM + c] * CS;
                const uint32 u = __float_as_uint(v);
                fh.u[j] = (unsigned short)(u >> 16);
                const float hif = __uint_as_float(u & 0xffff0000u);
                fl.u[j] = (unsigned short)(__float_as_uint(v - hif) >> 16);
            }
            Bhi[nt][kt] = fh.v;
            Blo[nt][kt] = fl.v;
        }
    }

    // ---- layer-1 params: this lane computes h cols 2l, 2l+1 (prescaled CS).
    const float2 w1x_ = *reinterpret_cast<const float2*>(&W1[2 * l]);
    const float2 w1s_ = *reinterpret_cast<const float2*>(&W1[HDIM + 2 * l]);
    const float2 b1v_ = *reinterpret_cast<const float2*>(&b1[2 * l]);
    const float2 w1x = make_float2(w1x_.x * CS, w1x_.y * CS);
    const float2 w1s = make_float2(w1s_.x * CS, w1s_.y * CS);
    const float2 b1v = make_float2(b1v_.x * CS, b1v_.y * CS);

    // ---- layer-2/3 params for this lane's two C-columns (cz, cz+16).
    const int cz = 32 * wv + (l & 15);
    const float b2a = b2[cz] * CS,  b2b = b2[cz + 16] * CS;
    const float w3a = W3[2 * cz + 1], w3b = W3[2 * (cz + 16) + 1];
    const float b31 = b3[1];

    // ---- LDS addresses.
    uint32* pWh = reinterpret_cast<uint32*>(&hbuf[wv][0][2 * l]);  // hi row
    uint32* pWl = reinterpret_cast<uint32*>(&hbuf[wv][1][2 * l]);  // lo row
    // A-frag read: lane supplies A[row=l&15]; row0=hi, row1=lo, rows 2-15 read
    // the lo row harmlessly (their C rows are never used).
    const int rowe = ((l & 15) == 0) ? 0 : 1;
    const unsigned short* pA = &hbuf[wv][rowe][8 * (l >> 4)];

    __syncthreads();

    float s = 0.0f, s_hold = 0.0f;
    float xn = xbuf[0];
    float2 pre1 = make_float2(fmaf(w1x.x, xn, b1v.x), fmaf(w1x.y, xn, b1v.y));

    for (int n = 0; n < SEQ; ++n) {
        const int par = n & 1;

        // ---- layer 1: 2 h cols; split to bf16 hi/lo; -> LDS rows 0/1.
        const float h0 = tanh_e2(fmaf(w1s.x, s, pre1.x));
        const float h1 = tanh_e2(fmaf(w1s.y, s, pre1.y));
        const uint32 u0 = __float_as_uint(h0), u1 = __float_as_uint(h1);
        const uint32 hi01 = __builtin_amdgcn_perm(u1, u0, 0x07060302u);
        const float r0 = h0 - __uint_as_float(u0 & 0xffff0000u);
        const float r1 = h1 - __uint_as_float(u1 & 0xffff0000u);
        const uint32 lo01 = __builtin_amdgcn_perm(
            __float_as_uint(r1), __float_as_uint(r0), 0x07060302u);
        *pWh = hi01;
        *pWl = lo01;
        __builtin_amdgcn_wave_barrier();   // in-wave LDS write -> read order

        // next x + next pre1 (broadcast read, off critical path)
        const float xnext = xbuf[(n + 1) & (SEQ - 1)];
        pre1 = make_float2(fmaf(w1x.x, xnext, b1v.x), fmaf(w1x.y, xnext, b1v.y));

        // ---- matvec on matrix pipe: 4 independent accum chains, 16 MFMA.
        // Row 0 of Ch* = hi*Bhi; row 1 = lo*Bhi; row 0 of Cl* = hi*Blo.
        f32x4 Ch0 = {b2a, b2a, b2a, b2a};
        f32x4 Ch1 = {b2b, b2b, b2b, b2b};
        f32x4 Cl0 = {0.0f, 0.0f, 0.0f, 0.0f};
        f32x4 Cl1 = {0.0f, 0.0f, 0.0f, 0.0f};
        #pragma unroll
        for (int kt = 0; kt < 4; ++kt) {
            const bf16x8 a = __builtin_bit_cast(bf16x8,
                *reinterpret_cast<const uint4*>(pA + 32 * kt));
            Ch0 = __builtin_amdgcn_mfma_f32_16x16x32_bf16(a, Bhi[0][kt], Ch0, 0, 0, 0);
            Ch1 = __builtin_amdgcn_mfma_f32_16x16x32_bf16(a, Bhi[1][kt], Ch1, 0, 0, 0);
            Cl0 = __builtin_amdgcn_mfma_f32_16x16x32_bf16(a, Blo[0][kt], Cl0, 0, 0, 0);
            Cl1 = __builtin_amdgcn_mfma_f32_16x16x32_bf16(a, Blo[1][kt], Cl1, 0, 0, 0);
        }
        __builtin_amdgcn_wave_barrier();   // reads precede next iter's writes

        // ---- combine 3 exact terms (valid on lanes 0-15: rows 0,1 live there).
        const float p0 = (Ch0[0] + Ch0[1]) + Cl0[0];
        const float p1 = (Ch1[0] + Ch1[1]) + Cl1[0];
        float z = fmaf(tanh_e2(p1), w3b, tanh_e2(p0) * w3a);

        // ---- reduce over 16 cols (lanes 0-15): xor1, xor2, xor4, xor8.
        z = dpp_add<0xB1>(z);    // quad_perm xor1
        z = dpp_add<0x4E>(z);    // quad_perm xor2
        z = dpp_add<0x141>(z);   // row_half_mirror == xor4 (quad-uniform)
        z = dpp_add<0x140>(z);   // row_mirror == xor8 (8-uniform)

        if (l == 0) ybuf[par][wv] = z;
        __syncthreads();   // the ONLY block barrier per step (vmcnt already 0)

        const float4 yv = *reinterpret_cast<const float4*>(&ybuf[par][0]);
        s += ((yv.x + yv.y) + (yv.z + yv.w)) + b31;

        // ---- out batching (wave 0): one scatter store per 64 steps.
        if (wv == 0) {
            if (l == (n & 63)) s_hold = s;
            if ((n & 63) == 63) out[(n - 63 + l) * BATCH + b] = s_hold;
        }
        xn = xnext;
    }
}

extern "C" void kernel_launch(void* const* d_in, const int* in_sizes, int n_in,
                              void* d_out, int out_size, void* d_ws, size_t ws_size,
                              hipStream_t stream) {
    const float* x  = (const float*)d_in[0];
    const float* W1 = (const float*)d_in[1];
    const float* b1 = (const float*)d_in[2];
    const float* W2 = (const float*)d_in[3];
    const float* b2 = (const float*)d_in[4];
    const float* W3 = (const float*)d_in[5];
    const float* b3 = (const float*)d_in[6];
    float* out = (float*)d_out;

    dim3 grid(BATCH);    // one chain per block -> 2 blocks/CU for latency hiding
    dim3 block(256);     // 4 waves, 32 N-cols each
    odenet_scan_kernel<<<grid, block, 0, stream>>>(x, W1, b1, W2, b2, W3, b3, out);
}